// Round 7
// baseline (4161.864 us; speedup 1.0000x reference)
//
#include <hip/hip_runtime.h>
#include <stdint.h>

// Farthest Point Sampling, persistent kernel. B=32, N=131072, S=1024.
// 16 chunk-blocks per batch (512 blocks x 512 threads, 2 blocks/CU so two
// DIFFERENT batches overlap per CU: one computes while the other waits on
// its rendezvous). Coords + running min-dist in registers (PPT=16 -> fits
// under the 128-VGPR cap, no AGPR parking). Fence-free rendezvous: relaxed
// agent-scope u64 keys, parity double-buffered, seq embedded as ready-flag.
// ALL waves poll the global slots (no second barrier, no LDS broadcast).

#define NB        32
#define NPTS      131072
#define NSAMP     1024
#define CHUNKS    16
#define THREADS   512
#define WAVES     (THREADS / 64)            // 8
#define PPT       (NPTS / (CHUNKS * THREADS))  // 16
#define CHUNK_PTS (NPTS / CHUNKS)           // 8192
#define BIGF      1e10f
#define SEQ_MASK  0x7FFFull   // s <= 1023; 0xAA poison seq = 0x2AAA never matches

// key layout: [dist_bits:32][NPTS-1-idx:17][seq:15]
// u64 max-compare == (dist desc, then idx asc); seq equal across slots of a round.
// Overwrite safety: slot for round s is next written at s+2, which requires all
// blocks posted s+1, which requires every wave of every block finished polling s.

__global__ __launch_bounds__(THREADS, 4)   // <=128 VGPR -> 16 waves/CU -> exactly 2 blocks/CU, all 512 resident
void fps_kernel(const float* __restrict__ pts,
                float* __restrict__ out,
                unsigned long long* __restrict__ keys)
{
    #pragma clang fp contract(off)   // match XLA's un-contracted (dx^2 + dy^2) + dz^2 (absmax=0 in R2/R6)

    const int b    = blockIdx.x & (NB - 1);   // same-batch blocks stride-32 apart -> same XCD under %8 round-robin
    const int c    = blockIdx.x >> 5;         // chunk 0..15
    const int t    = threadIdx.x;
    const int w    = t >> 6;
    const int lane = t & 63;

    __shared__ unsigned long long wkey[WAVES];   // per-wave argmax keys (only LDS left)

    const float* bpts = pts + (size_t)b * NPTS * 3;

    // Per-thread state in registers: 3x16 coords + 16 dists = 64 VGPRs.
    float x[PPT], y[PPT], z[PPT], dist[PPT];
    #pragma unroll
    for (int i = 0; i < PPT; ++i) {
        const int n = c * CHUNK_PTS + i * THREADS + t;   // lane-consecutive -> coalesced
        x[i] = bpts[3 * n + 0];
        y[i] = bpts[3 * n + 1];
        z[i] = bpts[3 * n + 2];
        dist[i] = BIGF;
    }

    // First selected point is index 0.
    float px = bpts[0], py = bpts[1], pz = bpts[2];
    if (c == 0 && t == 0) {
        out[(size_t)b * NSAMP * 3 + 0] = px;
        out[(size_t)b * NSAMP * 3 + 1] = py;
        out[(size_t)b * NSAMP * 3 + 2] = pz;
    }

    for (int s = 1; s < NSAMP; ++s) {
        // --- distance update + thread-local argmax (pure VALU, static indices) ---
        float bv = -1.0f;
        int   bi = 0;
        #pragma unroll
        for (int i = 0; i < PPT; ++i) {
            const float dx = x[i] - px;
            const float dy = y[i] - py;
            const float dz = z[i] - pz;
            float d = dx * dx;
            d = d + dy * dy;
            d = d + dz * dz;
            const float nd = fminf(dist[i], d);
            dist[i] = nd;
            if (nd > bv) { bv = nd; bi = c * CHUNK_PTS + i * THREADS + t; }
            // strict '>' keeps earliest (lowest) index within the thread
        }

        // --- wave argmax (64 lanes), tie -> lower global index ---
        #pragma unroll
        for (int off = 32; off > 0; off >>= 1) {
            const float ov = __shfl_xor(bv, off);
            const int   oi = __shfl_xor(bi, off);
            if (ov > bv || (ov == bv && oi < bi)) { bv = ov; bi = oi; }
        }
        if (lane == 0) {
            wkey[w] = ((unsigned long long)__float_as_uint(bv) << 32)
                    | ((unsigned long long)(NPTS - 1 - bi) << 15)
                    | (unsigned long long)s;
        }
        __syncthreads();   // the ONLY block-wide barrier per round

        unsigned long long* kslot = keys + ((size_t)(s & 1) * NB + b) * CHUNKS;

        if (w == 0) {
            // block argmax over the 8 wave keys, then post this chunk's key
            unsigned long long k = (lane < WAVES) ? wkey[lane] : 0ull;
            #pragma unroll
            for (int off = 1; off < WAVES; off <<= 1) {
                const unsigned long long ok = __shfl_xor(k, off);
                if (ok > k) k = ok;
            }
            if (lane == 0)
                __hip_atomic_store(&kslot[c], k, __ATOMIC_RELAXED, __HIP_MEMORY_SCOPE_AGENT);
        }
        __atomic_signal_fence(__ATOMIC_SEQ_CST);   // compiler-only: post precedes polls

        // --- every wave polls all 16 slots (lanes 0..15), relaxed only ---
        unsigned long long pk = 0;
        if (lane < CHUNKS) {
            do {
                pk = __hip_atomic_load(&kslot[lane], __ATOMIC_RELAXED, __HIP_MEMORY_SCOPE_AGENT);
            } while ((pk & SEQ_MASK) != (unsigned long long)s);
        }
        #pragma unroll
        for (int off = 1; off < CHUNKS; off <<= 1) {   // butterfly within lanes 0..15
            const unsigned long long ok = __shfl_xor(pk, off);
            if (ok > pk) pk = ok;
        }
        pk = __shfl(pk, 0);   // broadcast winner key to lanes 16..63

        const int widx = (NPTS - 1) - (int)((pk >> 15) & 0x1FFFF);
        // wave-uniform address -> one transaction per wave, L1-hot after first wave
        px = bpts[3 * (size_t)widx + 0];
        py = bpts[3 * (size_t)widx + 1];
        pz = bpts[3 * (size_t)widx + 2];

        if (c == 0 && t == 0) {
            const size_t o = ((size_t)b * NSAMP + s) * 3;
            out[o + 0] = px; out[o + 1] = py; out[o + 2] = pz;
        }
    }
}

extern "C" void kernel_launch(void* const* d_in, const int* in_sizes, int n_in,
                              void* d_out, int out_size, void* d_ws, size_t ws_size,
                              hipStream_t stream)
{
    const float* pts = (const float*)d_in[0];
    float* out = (float*)d_out;

    // keys[2][NB][CHUNKS] u64 = 8192 B. No init needed: 0xAA poison has seq
    // bits 0x2AAA which never equals any round number s <= 1023.
    unsigned long long* keys = (unsigned long long*)d_ws;

    fps_kernel<<<dim3(NB * CHUNKS), dim3(THREADS), 0, stream>>>(pts, out, keys);
}

// Round 8
// 3685.239 us; speedup vs baseline: 1.1293x; 1.1293x over previous
//
#include <hip/hip_runtime.h>
#include <stdint.h>

// Farthest Point Sampling, persistent kernel. B=32, N=131072, S=1024.
// Structure = R6 (proven 3.17ms): 8 chunk-blocks/batch, 256 blocks x 512 thr,
// coords+dist in registers, single-wave fence-free rendezvous, LDS broadcast.
// NEW in R8: XCD-local FAST rendezvous slots accessed with sc0-only (L2-scope)
// inline-asm load/store — same-batch blocks share an XCD under round-robin
// dispatch, so L2 (~200cy) visibility replaces LLC (~700cy) round trips.
// A slow agent-scope slot is polled every 8th spin as a correctness backstop,
// so termination does NOT depend on workgroup->XCD placement (only speed does).

#define NB        32
#define NPTS      131072
#define NSAMP     1024
#define CHUNKS    8
#define THREADS   512
#define WAVES     (THREADS / 64)               // 8
#define PPT       (NPTS / (CHUNKS * THREADS))  // 32
#define CHUNK_PTS (NPTS / CHUNKS)              // 16384
#define BIGF      1e10f
#define SEQ_MASK  0x7FFFull   // s <= 1023; 0xAA poison seq = 0x2AAA never matches

// key layout: [dist_bits:32][NPTS-1-idx:17][seq:15]
// u64 max-compare == (dist desc, then idx asc); seq equal across slots of a round.
// Overwrite safety (per slot array): slot for round s is next written at s+2,
// which requires all blocks posted s+1, which requires all consumed round s.

__device__ __forceinline__ void post_fast(unsigned long long* p, unsigned long long v) {
    // sc0-only store: write-through to this XCD's L2 (visible to same-XCD sc0 loads)
    asm volatile("global_store_dwordx2 %0, %1, off sc0" :: "v"(p), "v"(v) : "memory");
}
__device__ __forceinline__ unsigned long long poll_fast(const unsigned long long* p) {
    unsigned long long r;
    // sc0-only load: bypass L1, read from L2 (fresh for same-XCD writers)
    asm volatile("global_load_dwordx2 %0, %1, off sc0\n\t"
                 "s_waitcnt vmcnt(0)"
                 : "=v"(r) : "v"(p) : "memory");
    return r;
}

__global__ __launch_bounds__(THREADS, 2)   // 256-VGPR cap; grid=256 -> 1 block/CU guaranteed resident
void fps_kernel(const float* __restrict__ pts,
                float* __restrict__ out,
                unsigned long long* __restrict__ fastk,
                unsigned long long* __restrict__ slowk)
{
    #pragma clang fp contract(off)   // match XLA's un-contracted (dx^2 + dy^2) + dz^2 (absmax=0 R2/R6/R7)

    const int b    = blockIdx.x & (NB - 1);   // same-batch blocks stride-32 -> same XCD under %8 round-robin
    const int c    = blockIdx.x >> 5;         // chunk 0..7
    const int t    = threadIdx.x;
    const int w    = t >> 6;
    const int lane = t & 63;

    __shared__ unsigned long long wkey[WAVES];
    __shared__ float bc_x, bc_y, bc_z;

    const float* bpts = pts + (size_t)b * NPTS * 3;

    float x[PPT], y[PPT], z[PPT], dist[PPT];
    #pragma unroll
    for (int i = 0; i < PPT; ++i) {
        const int n = c * CHUNK_PTS + i * THREADS + t;   // lane-consecutive -> coalesced
        x[i] = bpts[3 * n + 0];
        y[i] = bpts[3 * n + 1];
        z[i] = bpts[3 * n + 2];
        dist[i] = BIGF;
    }

    float px = bpts[0], py = bpts[1], pz = bpts[2];   // first selected point: index 0
    if (c == 0 && t == 0) {
        out[(size_t)b * NSAMP * 3 + 0] = px;
        out[(size_t)b * NSAMP * 3 + 1] = py;
        out[(size_t)b * NSAMP * 3 + 2] = pz;
    }

    for (int s = 1; s < NSAMP; ++s) {
        // --- distance update + thread-local argmax (registers, static indices) ---
        float bv = -1.0f;
        int   bi = 0;
        #pragma unroll
        for (int i = 0; i < PPT; ++i) {
            const float dx = x[i] - px;
            const float dy = y[i] - py;
            const float dz = z[i] - pz;
            float d = dx * dx;
            d = d + dy * dy;
            d = d + dz * dz;
            const float nd = fminf(dist[i], d);
            dist[i] = nd;
            if (nd > bv) { bv = nd; bi = c * CHUNK_PTS + i * THREADS + t; }
            // strict '>' keeps earliest (lowest) index within the thread
        }

        // --- wave argmax (64 lanes), tie -> lower global index ---
        #pragma unroll
        for (int off = 32; off > 0; off >>= 1) {
            const float ov = __shfl_xor(bv, off);
            const int   oi = __shfl_xor(bi, off);
            if (ov > bv || (ov == bv && oi < bi)) { bv = ov; bi = oi; }
        }
        if (lane == 0) {
            wkey[w] = ((unsigned long long)__float_as_uint(bv) << 32)
                    | ((unsigned long long)(NPTS - 1 - bi) << 15)
                    | (unsigned long long)s;
        }
        __syncthreads();

        if (w == 0) {   // wave 0 runs the cross-block rendezvous
            // block argmax over the 8 wave keys
            unsigned long long k = (lane < WAVES) ? wkey[lane] : 0ull;
            #pragma unroll
            for (int off = 1; off < WAVES; off <<= 1) {
                const unsigned long long ok = __shfl_xor(k, off);
                if (ok > k) k = ok;
            }
            unsigned long long* fslot = fastk + ((size_t)(s & 1) * NB + b) * CHUNKS; // 64B/line per batch
            unsigned long long* sslot = slowk + ((size_t)(s & 1) * NB + b) * CHUNKS;
            if (lane == 0) {
                post_fast(&fslot[c], k);                                              // L2-scope (fast)
                __hip_atomic_store(&sslot[c], k, __ATOMIC_RELAXED, __HIP_MEMORY_SCOPE_AGENT); // LLC backstop
            }
            __atomic_signal_fence(__ATOMIC_SEQ_CST);

            // lane j polls slot j: fast (L2) every spin, slow (LLC) every 8th as backstop
            unsigned long long pk = 0;
            if (lane < CHUNKS) {
                const unsigned long long want = (unsigned long long)s;
                int spin = 0;
                for (;;) {
                    pk = poll_fast(&fslot[lane]);
                    if ((pk & SEQ_MASK) == want) break;
                    if ((++spin & 7) == 0) {
                        pk = __hip_atomic_load(&sslot[lane], __ATOMIC_RELAXED, __HIP_MEMORY_SCOPE_AGENT);
                        if ((pk & SEQ_MASK) == want) break;
                    }
                }
            }
            // per-batch argmax over the 8 chunk keys
            #pragma unroll
            for (int off = 1; off < CHUNKS; off <<= 1) {
                const unsigned long long ok = __shfl_xor(pk, off);
                if (ok > pk) pk = ok;
            }
            if (lane == 0) {
                const int widx = (NPTS - 1) - (int)((pk >> 15) & 0x1FFFF);
                const float wx = bpts[3 * (size_t)widx + 0];
                const float wy = bpts[3 * (size_t)widx + 1];
                const float wz = bpts[3 * (size_t)widx + 2];
                bc_x = wx; bc_y = wy; bc_z = wz;
                if (c == 0) {
                    const size_t o = ((size_t)b * NSAMP + s) * 3;
                    out[o + 0] = wx; out[o + 1] = wy; out[o + 2] = wz;
                }
            }
        }
        __syncthreads();   // also orders wkey reuse for the next round
        px = bc_x; py = bc_y; pz = bc_z;
    }
}

extern "C" void kernel_launch(void* const* d_in, const int* in_sizes, int n_in,
                              void* d_out, int out_size, void* d_ws, size_t ws_size,
                              hipStream_t stream)
{
    const float* pts = (const float*)d_in[0];
    float* out = (float*)d_out;

    // fastk[2][NB][CHUNKS] u64 = 4096B at +0; slowk same at +4096.
    // No init needed: 0xAA poison seq (0x2AAA) never equals any s <= 1023,
    // for both the fast and slow slot arrays.
    unsigned long long* fastk = (unsigned long long*)d_ws;
    unsigned long long* slowk = (unsigned long long*)((char*)d_ws + 4096);

    fps_kernel<<<dim3(NB * CHUNKS), dim3(THREADS), 0, stream>>>(pts, out, fastk, slowk);
}

// Round 9
// 3302.217 us; speedup vs baseline: 1.2603x; 1.1160x over previous
//
#include <hip/hip_runtime.h>
#include <stdint.h>

// FPS, two-batch software-pipelined persistent kernel. B=32, N=131072, S=1024.
// 256 blocks x 512 threads; block = (pair, chunk): chunk c of batch pair
// (bA=pair, bB=pair+16), 16 chunks/batch. While batch A's rendezvous is in
// flight, the block computes batch B (and vice versa) -> LLC latency hidden.
// Rendezvous slot = 32B: [key][x][y][z], EACH u64 word tagged with the 15-bit
// round seq (self-validating; no fences, no multi-word atomicity assumption).
// Winner coords ride in the slot -> no dependent global gather on the
// critical path. blockIdx%8 == pair%8 -> a pair's 16 blocks share an XCD.

#define NB        32
#define NPTS      131072
#define NSAMP     1024
#define NCH       16
#define THREADS   512
#define WAVES     8
#define PPT       16          // NPTS / (NCH * THREADS)
#define CHUNK_PTS 8192        // NPTS / NCH
#define BIGF      1e10f
#define SEQ_MASK  0x7FFFull   // s <= 1023; 0xAA poison seq = 0x2AAA never matches

// word packing: key  = [dist_bits:32][NPTS-1-idx:17][seq:15]  (u64 max == dist desc, idx asc)
//               coord= [f32_bits:32 ][     0    :17][seq:15]

// Overwrite safety (per batch, as R6): slot(s) rewritten first at s+2, which
// requires all pair-blocks posted s+1, which requires each consumed s; barrier
// waitcnt drains poll loads before any later store is issued.

#define UPDATE_PHASE(X)                                                        \
  {                                                                            \
    const float px = bc##X[0], py = bc##X[1], pz = bc##X[2];                   \
    float bv = -1.0f; int bi = 0; float bx = 0.f, by = 0.f, bz2 = 0.f;         \
    _Pragma("unroll")                                                          \
    for (int i = 0; i < PPT; ++i) {                                            \
      const float dx = x##X[i] - px;                                           \
      const float dy = y##X[i] - py;                                           \
      const float dz = z##X[i] - pz;                                           \
      float dd = dx * dx; dd = dd + dy * dy; dd = dd + dz * dz;                \
      const float nd = fminf(d##X[i], dd); d##X[i] = nd;                       \
      if (nd > bv) { bv = nd; bi = c * CHUNK_PTS + i * THREADS + t;            \
                     bx = x##X[i]; by = y##X[i]; bz2 = z##X[i]; }              \
    }                                                                          \
    unsigned long long key = ((unsigned long long)__float_as_uint(bv) << 32)   \
                           | ((unsigned long long)(NPTS - 1 - bi) << 15);      \
    const unsigned long long okey = key;                                       \
    _Pragma("unroll")                                                          \
    for (int off = 32; off > 0; off >>= 1) {                                   \
      const unsigned long long o = __shfl_xor(key, off);                       \
      if (o > key) key = o;                                                    \
    }                                                                          \
    if (okey == key) { /* unique winner lane (idx distinct per lane) */        \
      wk##X[w] = key; wx##X[w] = bx; wy##X[w] = by; wz##X[w] = bz2;            \
    }                                                                          \
  }

#define POST_HALF(X, sPost)                                                    \
  {                                                                            \
    unsigned long long k = (lane < WAVES) ? wk##X[lane] : 0ull;                \
    float kx = 0.f, ky = 0.f, kz = 0.f;                                        \
    if (lane < WAVES) { kx = wx##X[lane]; ky = wy##X[lane]; kz = wz##X[lane]; }\
    const unsigned long long ok = k;                                           \
    _Pragma("unroll")                                                          \
    for (int off = 1; off < WAVES; off <<= 1) {                                \
      const unsigned long long o = __shfl_xor(k, off);                         \
      if (o > k) k = o;                                                        \
    }                                                                          \
    if (lane < WAVES && ok == k) {                                             \
      const unsigned long long sq = (unsigned long long)(sPost);               \
      unsigned long long* sp = slots +                                         \
        ((((size_t)((sPost) & 1)) * NB + b##X) * NCH + c) * 4;                 \
      __hip_atomic_store(&sp[0], k | sq, __ATOMIC_RELAXED, __HIP_MEMORY_SCOPE_AGENT); \
      __hip_atomic_store(&sp[1], ((unsigned long long)__float_as_uint(kx) << 32) | sq, __ATOMIC_RELAXED, __HIP_MEMORY_SCOPE_AGENT); \
      __hip_atomic_store(&sp[2], ((unsigned long long)__float_as_uint(ky) << 32) | sq, __ATOMIC_RELAXED, __HIP_MEMORY_SCOPE_AGENT); \
      __hip_atomic_store(&sp[3], ((unsigned long long)__float_as_uint(kz) << 32) | sq, __ATOMIC_RELAXED, __HIP_MEMORY_SCOPE_AGENT); \
    }                                                                          \
  }

#define POLL_HALF(Y, sPoll)                                                    \
  {                                                                            \
    unsigned long long k0 = 0, k1 = 0, k2 = 0, k3 = 0;                         \
    const unsigned long long sq = (unsigned long long)(sPoll);                 \
    if (lane < NCH) {                                                          \
      unsigned long long* sp = slots +                                         \
        ((((size_t)((sPoll) & 1)) * NB + b##Y) * NCH + lane) * 4;              \
      for (;;) {                                                               \
        k0 = __hip_atomic_load(&sp[0], __ATOMIC_RELAXED, __HIP_MEMORY_SCOPE_AGENT); \
        k1 = __hip_atomic_load(&sp[1], __ATOMIC_RELAXED, __HIP_MEMORY_SCOPE_AGENT); \
        k2 = __hip_atomic_load(&sp[2], __ATOMIC_RELAXED, __HIP_MEMORY_SCOPE_AGENT); \
        k3 = __hip_atomic_load(&sp[3], __ATOMIC_RELAXED, __HIP_MEMORY_SCOPE_AGENT); \
        if (((k0 & SEQ_MASK) == sq) & ((k1 & SEQ_MASK) == sq) &                \
            ((k2 & SEQ_MASK) == sq) & ((k3 & SEQ_MASK) == sq)) break;          \
      }                                                                        \
    }                                                                          \
    const unsigned long long ok0 = k0;                                         \
    unsigned long long m = k0;                                                 \
    _Pragma("unroll")                                                          \
    for (int off = 1; off < NCH; off <<= 1) {                                  \
      const unsigned long long o = __shfl_xor(m, off);                         \
      if (o > m) m = o;                                                        \
    }                                                                          \
    if (lane < NCH && ok0 == m) { /* unique winner chunk */                    \
      const float gx = __uint_as_float((unsigned)(k1 >> 32));                  \
      const float gy = __uint_as_float((unsigned)(k2 >> 32));                  \
      const float gz = __uint_as_float((unsigned)(k3 >> 32));                  \
      bc##Y[0] = gx; bc##Y[1] = gy; bc##Y[2] = gz;                             \
      if (c == 0) {                                                            \
        const size_t o_ = ((size_t)b##Y * NSAMP + (sPoll)) * 3;                \
        out[o_ + 0] = gx; out[o_ + 1] = gy; out[o_ + 2] = gz;                  \
      }                                                                        \
    }                                                                          \
  }

__global__ __launch_bounds__(THREADS, 2)   // 256-VGPR cap; grid=256 -> 1 block/CU guaranteed
void fps_kernel(const float* __restrict__ pts,
                float* __restrict__ out,
                unsigned long long* __restrict__ slots)
{
    #pragma clang fp contract(off)   // match XLA's un-contracted (dx^2+dy^2)+dz^2 (absmax=0 R2/R6/R7/R8)

    const int pair = blockIdx.x & 15;      // blockIdx%8 == pair%8 -> pair's blocks share an XCD
    const int c    = blockIdx.x >> 4;      // chunk 0..15
    const int bA   = pair, bB = pair + 16;
    const int t    = threadIdx.x;
    const int w    = t >> 6;
    const int lane = t & 63;

    __shared__ unsigned long long wkA[WAVES], wkB[WAVES];
    __shared__ float wxA[WAVES], wyA[WAVES], wzA[WAVES];
    __shared__ float wxB[WAVES], wyB[WAVES], wzB[WAVES];
    __shared__ float bcA[3], bcB[3];

    const float* pA = pts + (size_t)bA * NPTS * 3;
    const float* pB = pts + (size_t)bB * NPTS * 3;

    // Per-thread state: 2 batches x (3x16 coords + 16 dist) = 128 floats.
    float xA[PPT], yA[PPT], zA[PPT], dA[PPT];
    float xB[PPT], yB[PPT], zB[PPT], dB[PPT];
    #pragma unroll
    for (int i = 0; i < PPT; ++i) {
        const int n = c * CHUNK_PTS + i * THREADS + t;   // lane-consecutive -> coalesced
        xA[i] = pA[3*n+0]; yA[i] = pA[3*n+1]; zA[i] = pA[3*n+2]; dA[i] = BIGF;
        xB[i] = pB[3*n+0]; yB[i] = pB[3*n+1]; zB[i] = pB[3*n+2]; dB[i] = BIGF;
    }

    // Round 0 winner = point 0 for both batches.
    if (t == 0) {
        bcA[0] = pA[0]; bcA[1] = pA[1]; bcA[2] = pA[2];
        bcB[0] = pB[0]; bcB[1] = pB[1]; bcB[2] = pB[2];
    }
    if (c == 0 && t == 0) {
        out[(size_t)bA*NSAMP*3 + 0] = pA[0]; out[(size_t)bA*NSAMP*3 + 1] = pA[1]; out[(size_t)bA*NSAMP*3 + 2] = pA[2];
        out[(size_t)bB*NSAMP*3 + 0] = pB[0]; out[(size_t)bB*NSAMP*3 + 1] = pB[1]; out[(size_t)bB*NSAMP*3 + 2] = pB[2];
    }
    __syncthreads();

    // Prologue: phase A(1) — update+post only (B has nothing to poll yet).
    UPDATE_PHASE(A)
    __syncthreads();
    if (w == 0) { POST_HALF(A, 1) }
    // no second barrier needed: next phase touches wkB/bcB only, and its own
    // leading barrier orders everything.

    // Steady state: each iteration completes round s for BOTH batches.
    // Phase(B,s): update B (winB(s-1)), post B(s) || poll A(s) -> bcA, out A(s)
    // Phase(A,s+1): update A (winA(s)), post A(s+1) || poll B(s) -> bcB, out B(s)
    for (int s = 1; s < NSAMP; ++s) {
        UPDATE_PHASE(B)
        __syncthreads();
        if      (w == 0) { POST_HALF(B, s) }
        else if (w == 1) { POLL_HALF(A, s) }
        __syncthreads();

        if (s < NSAMP - 1) {
            UPDATE_PHASE(A)
            __syncthreads();
            if      (w == 0) { POST_HALF(A, s + 1) }
            else if (w == 1) { POLL_HALF(B, s) }
            __syncthreads();
        }
    }

    // Epilogue: B(1023) was posted but never polled -> emit its output.
    if (w == 1) { POLL_HALF(B, NSAMP - 1) }
}

extern "C" void kernel_launch(void* const* d_in, const int* in_sizes, int n_in,
                              void* d_out, int out_size, void* d_ws, size_t ws_size,
                              hipStream_t stream)
{
    const float* pts = (const float*)d_in[0];
    float* out = (float*)d_out;

    // slots[2][NB][NCH][4] u64 = 32 KiB. No init needed: 0xAA poison seq
    // (0x2AAA) never equals any round s <= 1023, for every slot word.
    unsigned long long* slots = (unsigned long long*)d_ws;

    fps_kernel<<<dim3(256), dim3(THREADS), 0, stream>>>(pts, out, slots);
}